// Round 1
// baseline (426.784 us; speedup 1.0000x reference)
//
#include <hip/hip_runtime.h>
#include <stdint.h>

// Problem constants (fixed by reference setup_inputs)
#define D_DIM 4096      // hidden dim (K)
#define E_NUM 64        // experts (N)
#define T_TOK 16384     // tokens (M) = 4*4096
#define CAPF 256.0f     // expert_capacity = int(16384/64*1.0)
#define NSTEP 16        // K steps of BK=256 floats
#define ROWS 32         // tokens per block

using bf16x8 = __attribute__((ext_vector_type(8))) short;
using f32x4  = __attribute__((ext_vector_type(4))) float;
typedef unsigned short u16;
typedef unsigned int u32;

// Truncation split: x == hi + lo exactly; lo then truncated to bf16 (err <= 2^-17 |x|).
__device__ __forceinline__ void cvt8(const float4 a, const float4 b, bf16x8& h, bf16x8& l) {
  float f[8] = {a.x, a.y, a.z, a.w, b.x, b.y, b.z, b.w};
#pragma unroll
  for (int i = 0; i < 8; ++i) {
    u32 u = __float_as_uint(f[i]);
    float lo = f[i] - __uint_as_float(u & 0xFFFF0000u);
    h[i] = (short)(u >> 16);
    l[i] = (short)(__float_as_uint(lo) >> 16);
  }
}

// Kernel 0: W (4096x64, [k][e]) -> Wp/Wlp packed in MFMA B-fragment order:
//   Wp[((kk*4 + ct)*64 + lane)*8 + i] = hi(W[kk*32 + (lane>>4)*8 + i][ct*16 + (lane&15)])
// so the GEMM's B-load is base + lane*16 (fully coalesced), no gathers.
__global__ __launch_bounds__(256) void prep_kernel(const float* __restrict__ W,
                                                   u16* __restrict__ Wp, u16* __restrict__ Wlp) {
  const int t = blockIdx.x * 256 + threadIdx.x;   // 32768 threads, one 16B chunk each
  const int lane = t & 63;
  const int ct = (t >> 6) & 3;
  const int kk = t >> 8;
  const int e = ct * 16 + (lane & 15);
  const int k0 = kk * 32 + (lane >> 4) * 8;
  u32 hp[4], lp[4];
#pragma unroll
  for (int j = 0; j < 4; ++j) {
    u32 hh[2], ll[2];
#pragma unroll
    for (int q = 0; q < 2; ++q) {
      float w = W[(size_t)(k0 + 2 * j + q) * E_NUM + e];
      u32 u = __float_as_uint(w);
      float lo = w - __uint_as_float(u & 0xFFFF0000u);
      hh[q] = u >> 16;
      ll[q] = __float_as_uint(lo) >> 16;
    }
    hp[j] = hh[0] | (hh[1] << 16);
    lp[j] = ll[0] | (ll[1] << 16);
  }
  *(uint4*)(Wp  + (size_t)t * 8) = make_uint4(hp[0], hp[1], hp[2], hp[3]);
  *(uint4*)(Wlp + (size_t)t * 8) = make_uint4(lp[0], lp[1], lp[2], lp[3]);
}

// Kernel 1: barrier-free router GEMM + softmax + top-1.
// Block: 256 thr = 4 waves, 32 tokens. Wave kh: 32 tokens x 64 experts over
// K-quarter columns s*256 + kh*64 .. +64 of each step. A (x) is loaded DIRECTLY
// global->register: LDS staging had zero reuse (each x element is consumed by
// exactly one wave's one fragment), so the old DMA+__syncthreads pipeline was
// pure latency cost (MfmaUtil 6%, VALUBusy 6%, HBM 11% -> latency/barrier-bound).
// A is register-double-buffered (prefetch distance >= 1 full K-step ~ 6.5k cy
// >> ~900 cy HBM latency); B comes from the L2-resident packed Wp/Wlp as fully
// coalesced 1KB wave-loads. No __syncthreads until the epilogue combine.
__global__ __launch_bounds__(256, 2) void gemm_softmax(
    const float* __restrict__ x, const u16* __restrict__ Wp, const u16* __restrict__ Wlp,
    const float* __restrict__ bias, float* __restrict__ out,
    float* __restrict__ S, float* __restrict__ P,
    float* __restrict__ top_p, int* __restrict__ top_i) {
  __shared__ float smem[4 * 2112];   // epilogue combine slab only (33.8 KB)

  const int tid = threadIdx.x;
  const int lane = tid & 63;
  const int kh = tid >> 6;       // K-quarter (wave id)
  const int m = lane & 15;       // token-in-tile (A row)
  const int g = lane >> 4;       // k-octet
  const int tok_base = blockIdx.x * ROWS;

  f32x4 acc[2][4];               // [row-tile][col-tile]
#pragma unroll
  for (int rt = 0; rt < 2; ++rt)
#pragma unroll
    for (int ct = 0; ct < 4; ++ct) acc[rt][ct] = (f32x4){0.f, 0.f, 0.f, 0.f};

  // Per-lane A row bases. Per instruction the wave reads 16 rows x 16B at 32B
  // stride; the paired +4 load covers the complementary 16B, so every 128B
  // line is fully consumed by the instruction pair.
  const float* pa0 = x + (size_t)(tok_base + m) * D_DIM + kh * 64 + g * 8;
  const float* pa1 = pa0 + (size_t)16 * D_DIM;

  float4 aA[2][2][2], aB[2][2][2];   // [j][rt][half] — two named buffers (no runtime idx -> no scratch)

  auto loadA = [&](float4 (&dst)[2][2][2], int s) {
    const int c = s * 256;
#pragma unroll
    for (int j = 0; j < 2; ++j) {
      const float* q0 = pa0 + c + j * 32;
      const float* q1 = pa1 + c + j * 32;
      dst[j][0][0] = *(const float4*)(q0);
      dst[j][0][1] = *(const float4*)(q0 + 4);
      dst[j][1][0] = *(const float4*)(q1);
      dst[j][1][1] = *(const float4*)(q1 + 4);
    }
  };

  auto step = [&](const float4 (&af)[2][2][2], int s) {
    // B fragments, packed-coalesced: 16 x 1KB contiguous wave-loads from L2
    bf16x8 bh[2][4], bl[2][4];
#pragma unroll
    for (int j = 0; j < 2; ++j) {
      const int kk = s * 8 + kh * 2 + j;        // k32-chunk index
#pragma unroll
      for (int ct = 0; ct < 4; ++ct) {
        const size_t o = ((size_t)(kk * 4 + ct) * 64 + lane) * 8;
        bh[j][ct] = *(const bf16x8*)(Wp + o);
        bl[j][ct] = *(const bf16x8*)(Wlp + o);
      }
    }
#pragma unroll
    for (int j = 0; j < 2; ++j)
#pragma unroll
      for (int rt = 0; rt < 2; ++rt) {
        bf16x8 ah, al;                           // short live range
        cvt8(af[j][rt][0], af[j][rt][1], ah, al);
#pragma unroll
        for (int ct = 0; ct < 4; ++ct) {
          acc[rt][ct] = __builtin_amdgcn_mfma_f32_16x16x32_bf16(ah, bh[j][ct], acc[rt][ct], 0, 0, 0);
          acc[rt][ct] = __builtin_amdgcn_mfma_f32_16x16x32_bf16(al, bh[j][ct], acc[rt][ct], 0, 0, 0);
          acc[rt][ct] = __builtin_amdgcn_mfma_f32_16x16x32_bf16(ah, bl[j][ct], acc[rt][ct], 0, 0, 0);
        }
      }
  };

  // Software pipeline, 2-deep A register double-buffer, no barriers:
  //   iter: loadA(aB,s+1) | step(aA,s) | loadA(aA,s+2) | step(aB,s+1)
  loadA(aA, 0);
#pragma unroll 1
  for (int s = 0; s < NSTEP; s += 2) {
    loadA(aB, s + 1);
    step(aA, s);
    if (s + 2 < NSTEP) loadA(aA, s + 2);
    step(aB, s + 1);
  }

  // ---- combine K-quarters via slab[4][32][66] ----
  // C/D layout: token-in-tile = g*4+r, expert-in-tile = m (verified rounds 1-3)
#pragma unroll
  for (int rt = 0; rt < 2; ++rt)
#pragma unroll
    for (int ct = 0; ct < 4; ++ct)
#pragma unroll
      for (int r = 0; r < 4; ++r)
        smem[kh * 2112 + (rt * 16 + g * 4 + r) * 66 + ct * 16 + m] = acc[rt][ct][r];
  __syncthreads();

  // softmax: 8 threads per token, 8 experts each
  const int j = tid >> 3;
  const int q = tid & 7;
  float v[8];
#pragma unroll
  for (int i = 0; i < 8; ++i) {
    const int e = q * 8 + i;
    v[i] = bias[e] + smem[j * 66 + e] + smem[2112 + j * 66 + e]
                   + smem[4224 + j * 66 + e] + smem[6336 + j * 66 + e];
  }
  float best = v[0]; int bi = q * 8;
#pragma unroll
  for (int i = 1; i < 8; ++i)
    if (v[i] > best) { best = v[i]; bi = q * 8 + i; }
#pragma unroll
  for (int d = 1; d <= 4; d <<= 1) {   // reduce across the 8-lane token group
    float ob = __shfl_xor(best, d);
    int oi = __shfl_xor(bi, d);
    if (ob > best || (ob == best && oi < bi)) { best = ob; bi = oi; }
  }
  float ex[8], ssum = 0.f;
#pragma unroll
  for (int i = 0; i < 8; ++i) { ex[i] = __expf(v[i] - best); ssum += ex[i]; }
#pragma unroll
  for (int d = 1; d <= 4; d <<= 1) ssum += __shfl_xor(ssum, d);
  const float rs = 1.0f / ssum;

  const int gt = tok_base + j;
#pragma unroll
  for (int i = 0; i < 8; ++i) {
    float p = ex[i] * rs;
    out[(size_t)gt * 64 + q * 8 + i] = p;
    smem[j * 66 + q * 8 + i] = p;     // own slots only (safe without barrier)
  }
  if (q == 0) {
    top_p[gt] = rs;                    // top prob = exp(best-best)/ssum
    top_i[gt] = bi;
    atomicAdd(&S[bi], rs);
  }
  __syncthreads();
  if (tid < 64) {                      // per-expert prob sums over 32 tokens
    float sa = 0.f;
#pragma unroll
    for (int jj = 0; jj < ROWS; ++jj) sa += smem[jj * 66 + tid];
    atomicAdd(&P[tid], sa);
  }
}

// Kernel 2: aux loss scalar
__global__ __launch_bounds__(64) void aux_kernel(float* __restrict__ out,
                                                 const float* __restrict__ S,
                                                 const float* __restrict__ P) {
  int l = threadIdx.x;
  float v = S[l] * P[l];
#pragma unroll
  for (int d = 1; d <= 32; d <<= 1) v += __shfl_xor(v, d);
  if (l == 0) out[(size_t)T_TOK * E_NUM] = 0.01f * 64.0f * v / ((float)T_TOK * (float)T_TOK);
}

// Kernel 3: capacity masking. Fast path: expert top-prob sum <= 256 -> all tokens kept
// (cumsum monotone, probs > 0). Exact O(T) scan only if an expert overflows.
__global__ __launch_bounds__(256) void finalize_kernel(float* __restrict__ out,
                                                       const float* __restrict__ top_p,
                                                       const int* __restrict__ top_i,
                                                       const float* __restrict__ S) {
  int t = blockIdx.x * 256 + threadIdx.x;
  int e = top_i[t];
  float se = S[e];
  if (se > CAPF) {
    float p = top_p[t];
    float G = 0.f;
    for (int u = 0; u < T_TOK; ++u) {
      if (top_i[u] == e) {
        float q = top_p[u];
        if (q > p || (q == p && u <= t)) G += q;
      }
    }
    if (G > CAPF) {
      float4 z = {0.f, 0.f, 0.f, 0.f};
      float4* row = (float4*)(out + (size_t)t * 64);
#pragma unroll
      for (int i = 0; i < 16; ++i) row[i] = z;
    }
  }
}

extern "C" void kernel_launch(void* const* d_in, const int* in_sizes, int n_in,
                              void* d_out, int out_size, void* d_ws, size_t ws_size,
                              hipStream_t stream) {
  const float* x = (const float*)d_in[0];
  const float* W = (const float*)d_in[1];
  const float* b = (const float*)d_in[2];
  float* out = (float*)d_out;

  // ws layout (~1.2 MB)
  u16* Wp = (u16*)d_ws;
  u16* Wlp = Wp + (size_t)E_NUM * D_DIM;
  float* S = (float*)(Wlp + (size_t)E_NUM * D_DIM);
  float* P = S + 64;
  float* top_p = P + 64;
  int* top_i = (int*)(top_p + T_TOK);

  hipMemsetAsync(S, 0, 2 * 64 * sizeof(float), stream);
  prep_kernel<<<128, 256, 0, stream>>>(W, Wp, Wlp);
  gemm_softmax<<<T_TOK / ROWS, 256, 0, stream>>>(x, Wp, Wlp, b, out, S, P, top_p, top_i);
  aux_kernel<<<1, 64, 0, stream>>>(out, S, P);
  finalize_kernel<<<T_TOK / 256, 256, 0, stream>>>(out, top_p, top_i, S);
}

// Round 2
// 422.139 us; speedup vs baseline: 1.0110x; 1.0110x over previous
//
#include <hip/hip_runtime.h>
#include <stdint.h>

// Problem constants (fixed by reference setup_inputs)
#define D_DIM 4096      // hidden dim (K)
#define E_NUM 64        // experts (N)
#define T_TOK 16384     // tokens (M) = 4*4096
#define CAPF 256.0f     // expert_capacity = int(16384/64*1.0)
#define ROWS 16         // tokens per block
#define NBLK (T_TOK / ROWS)   // 1024 blocks -> 4 blocks/CU -> 16 waves/CU

using bf16x8 = __attribute__((ext_vector_type(8))) short;
using f32x4  = __attribute__((ext_vector_type(4))) float;
typedef unsigned short u16;
typedef unsigned int u32;

// Truncation split: x == hi + lo exactly; lo then truncated to bf16 (err <= 2^-17 |x|).
__device__ __forceinline__ void cvt8(const float4 a, const float4 b, bf16x8& h, bf16x8& l) {
  float f[8] = {a.x, a.y, a.z, a.w, b.x, b.y, b.z, b.w};
#pragma unroll
  for (int i = 0; i < 8; ++i) {
    u32 u = __float_as_uint(f[i]);
    float lo = f[i] - __uint_as_float(u & 0xFFFF0000u);
    h[i] = (short)(u >> 16);
    l[i] = (short)(__float_as_uint(lo) >> 16);
  }
}

// Kernel 0: W (4096x64, [k][e]) -> Wp/Wlp packed in MFMA B-fragment order:
//   Wp[((kk*4 + ct)*64 + lane)*8 + i] = hi(W[kk*32 + (lane>>4)*8 + i][ct*16 + (lane&15)])
// so the GEMM's B-load is base + lane*16 (fully coalesced), no gathers.
__global__ __launch_bounds__(256) void prep_kernel(const float* __restrict__ W,
                                                   u16* __restrict__ Wp, u16* __restrict__ Wlp) {
  const int t = blockIdx.x * 256 + threadIdx.x;   // 32768 threads, one 16B chunk each
  const int lane = t & 63;
  const int ct = (t >> 6) & 3;
  const int kk = t >> 8;
  const int e = ct * 16 + (lane & 15);
  const int k0 = kk * 32 + (lane >> 4) * 8;
  u32 hp[4], lp[4];
#pragma unroll
  for (int j = 0; j < 4; ++j) {
    u32 hh[2], ll[2];
#pragma unroll
    for (int q = 0; q < 2; ++q) {
      float w = W[(size_t)(k0 + 2 * j + q) * E_NUM + e];
      u32 u = __float_as_uint(w);
      float lo = w - __uint_as_float(u & 0xFFFF0000u);
      hh[q] = u >> 16;
      ll[q] = __float_as_uint(lo) >> 16;
    }
    hp[j] = hh[0] | (hh[1] << 16);
    lp[j] = ll[0] | (ll[1] << 16);
  }
  *(uint4*)(Wp  + (size_t)t * 8) = make_uint4(hp[0], hp[1], hp[2], hp[3]);
  *(uint4*)(Wlp + (size_t)t * 8) = make_uint4(lp[0], lp[1], lp[2], lp[3]);
}

// Kernel 1: router GEMM + softmax + top-1.  16 tokens/block, 4 waves, wave kh
// owns the contiguous K-quarter [kh*1024, kh*1024+1024).  Rationale vs r1:
// both prior versions (LDS-DMA and reg-dbuf) plateaued identically at 163us,
// MfmaUtil~6 VALUBusy~6 HBM~11 Occupancy~20 -> machine-wide latency bound:
// grid 512 capped us at 8 waves/CU and VGPR pressure (92 regs for a ~160-reg
// working set) made the compiler sink the prefetch.  This version: 1024
// blocks (16 waves/CU), ~100-reg working set pinned by launch_bounds(256,4)
// so the 2-deep A register pipeline survives, and ZERO global atomics
// (per-block partials + separate reduction kernel) to kill the S/P
// same-line RMW serialization shared by both prior versions.
__global__ __launch_bounds__(256, 4) void gemm_softmax(
    const float* __restrict__ x, const u16* __restrict__ Wp, const u16* __restrict__ Wlp,
    const float* __restrict__ bias, float* __restrict__ out,
    float* __restrict__ Spart, float* __restrict__ Ppart,
    float* __restrict__ top_p, int* __restrict__ top_i) {
  __shared__ float smem[4 * 16 * 66];   // per-quarter partial logits slab (16.9 KB)
  __shared__ float S_loc[64];           // per-block top-prob sums (LDS atomics)

  const int tid = threadIdx.x;
  const int lane = tid & 63;
  const int kh = tid >> 6;       // K-quarter (wave id)
  const int m = lane & 15;       // token-in-tile (A row)
  const int g = lane >> 4;       // k-octet
  const int tok_base = blockIdx.x * ROWS;

  if (tid < 64) S_loc[tid] = 0.f;   // covered by the pre-epilogue barrier

  f32x4 acc[4];                  // [col-tile]
#pragma unroll
  for (int ct = 0; ct < 4; ++ct) acc[ct] = (f32x4){0.f, 0.f, 0.f, 0.f};

  // Per-lane A base: row tok_base+m, col kh*1024 + g*8.  Per load instr the
  // wave reads 16 rows x 64B (4 g-groups x 16B); the +4 pair completes each
  // 128B line, so lines are fully consumed.
  const float* pa = x + (size_t)(tok_base + m) * D_DIM + kh * 1024 + g * 8;

  float4 aA[2][2], aB[2][2];     // [j][half] — named buffers, no runtime idx

  auto loadA = [&](float4 (&dst)[2][2], int s) {
    const float* q = pa + s * 64;
    dst[0][0] = *(const float4*)(q);
    dst[0][1] = *(const float4*)(q + 4);
    dst[1][0] = *(const float4*)(q + 32);
    dst[1][1] = *(const float4*)(q + 36);
  };

  auto step = [&](const float4 (&af)[2][2], int s) {
#pragma unroll
    for (int j = 0; j < 2; ++j) {          // one k32-chunk per half-step: B live range = 32 regs
      const int kk = kh * 32 + s * 2 + j;
      bf16x8 bh[4], bl[4];
#pragma unroll
      for (int ct = 0; ct < 4; ++ct) {
        const size_t o = ((size_t)(kk * 4 + ct) * 64 + lane) * 8;
        bh[ct] = *(const bf16x8*)(Wp + o);
        bl[ct] = *(const bf16x8*)(Wlp + o);
      }
      bf16x8 ah, al;
      cvt8(af[j][0], af[j][1], ah, al);
#pragma unroll
      for (int ct = 0; ct < 4; ++ct) {
        acc[ct] = __builtin_amdgcn_mfma_f32_16x16x32_bf16(ah, bh[ct], acc[ct], 0, 0, 0);
        acc[ct] = __builtin_amdgcn_mfma_f32_16x16x32_bf16(al, bh[ct], acc[ct], 0, 0, 0);
        acc[ct] = __builtin_amdgcn_mfma_f32_16x16x32_bf16(ah, bl[ct], acc[ct], 0, 0, 0);
      }
    }
  };

  // Software pipeline, 2-deep A register double-buffer, no barriers.
  loadA(aA, 0);
#pragma unroll 1
  for (int s = 0; s < 16; s += 2) {        // 16 steps x 64 cols = 1024 cols
    loadA(aB, s + 1);
    step(aA, s);
    if (s + 2 < 16) loadA(aA, s + 2);
    step(aB, s + 1);
  }

  // ---- combine K-quarters via slab[4][16][66] ----
  // C/D layout: token-in-tile = g*4+r, expert-in-tile = ct*16+m (verified)
#pragma unroll
  for (int ct = 0; ct < 4; ++ct)
#pragma unroll
    for (int r = 0; r < 4; ++r)
      smem[kh * 1056 + (g * 4 + r) * 66 + ct * 16 + m] = acc[ct][r];
  __syncthreads();

  // softmax: 16 threads per token, 4 experts each
  const int j = tid >> 4;        // token 0..15
  const int q = tid & 15;
  float v[4];
#pragma unroll
  for (int i = 0; i < 4; ++i) {
    const int e = q * 4 + i;
    v[i] = bias[e] + smem[j * 66 + e] + smem[1056 + j * 66 + e]
                   + smem[2112 + j * 66 + e] + smem[3168 + j * 66 + e];
  }
  float best = v[0]; int bi = q * 4;
#pragma unroll
  for (int i = 1; i < 4; ++i)
    if (v[i] > best) { best = v[i]; bi = q * 4 + i; }
#pragma unroll
  for (int d = 1; d <= 8; d <<= 1) {   // reduce across the 16-lane token group
    float ob = __shfl_xor(best, d);
    int oi = __shfl_xor(bi, d);
    if (ob > best || (ob == best && oi < bi)) { best = ob; bi = oi; }
  }
  float ex[4], ssum = 0.f;
#pragma unroll
  for (int i = 0; i < 4; ++i) { ex[i] = __expf(v[i] - best); ssum += ex[i]; }
#pragma unroll
  for (int d = 1; d <= 8; d <<= 1) ssum += __shfl_xor(ssum, d);
  const float rs = 1.0f / ssum;

  const int gt = tok_base + j;
#pragma unroll
  for (int i = 0; i < 4; ++i) {
    float p = ex[i] * rs;
    out[(size_t)gt * 64 + q * 4 + i] = p;
    smem[j * 66 + q * 4 + i] = p;     // each thread rewrites exactly the slots it read
  }
  if (q == 0) {
    top_p[gt] = rs;                    // top prob = exp(best-best)/ssum
    top_i[gt] = bi;
    atomicAdd(&S_loc[bi], rs);         // LDS atomic — no global contention
  }
  __syncthreads();
  if (tid < 64) {                      // per-expert partials for this block
    float sa = 0.f;
#pragma unroll
    for (int jj = 0; jj < ROWS; ++jj) sa += smem[jj * 66 + tid];
    Ppart[(size_t)blockIdx.x * 64 + tid] = sa;
    Spart[(size_t)blockIdx.x * 64 + tid] = S_loc[tid];
  }
}

// Kernel 2: reduce per-block partials -> Stot (for finalize) + aux loss scalar.
__global__ __launch_bounds__(256) void aux_kernel(float* __restrict__ out,
                                                  const float* __restrict__ Spart,
                                                  const float* __restrict__ Ppart,
                                                  float* __restrict__ Stot) {
  __shared__ float sS[4][64], sP[4][64];
  const int l = threadIdx.x & 63;
  const int c = threadIdx.x >> 6;
  float ss = 0.f, pp = 0.f;
#pragma unroll 4
  for (int b = c * (NBLK / 4); b < (c + 1) * (NBLK / 4); ++b) {
    ss += Spart[(size_t)b * 64 + l];    // 64 lanes read 256B contiguous
    pp += Ppart[(size_t)b * 64 + l];
  }
  sS[c][l] = ss; sP[c][l] = pp;
  __syncthreads();
  if (threadIdx.x < 64) {
    float Sv = sS[0][l] + sS[1][l] + sS[2][l] + sS[3][l];
    float Pv = sP[0][l] + sP[1][l] + sP[2][l] + sP[3][l];
    Stot[l] = Sv;
    float v = Sv * Pv;
#pragma unroll
    for (int d = 1; d <= 32; d <<= 1) v += __shfl_xor(v, d);
    if (l == 0) out[(size_t)T_TOK * E_NUM] = 0.01f * 64.0f * v / ((float)T_TOK * (float)T_TOK);
  }
}

// Kernel 3: capacity masking. Fast path: expert top-prob sum <= 256 -> all tokens kept
// (cumsum monotone, probs > 0). Exact O(T) scan only if an expert overflows.
__global__ __launch_bounds__(256) void finalize_kernel(float* __restrict__ out,
                                                       const float* __restrict__ top_p,
                                                       const int* __restrict__ top_i,
                                                       const float* __restrict__ Stot) {
  int t = blockIdx.x * 256 + threadIdx.x;
  int e = top_i[t];
  float se = Stot[e];
  if (se > CAPF) {
    float p = top_p[t];
    float G = 0.f;
    for (int u = 0; u < T_TOK; ++u) {
      if (top_i[u] == e) {
        float q = top_p[u];
        if (q > p || (q == p && u <= t)) G += q;
      }
    }
    if (G > CAPF) {
      float4 z = {0.f, 0.f, 0.f, 0.f};
      float4* row = (float4*)(out + (size_t)t * 64);
#pragma unroll
      for (int i = 0; i < 16; ++i) row[i] = z;
    }
  }
}

extern "C" void kernel_launch(void* const* d_in, const int* in_sizes, int n_in,
                              void* d_out, int out_size, void* d_ws, size_t ws_size,
                              hipStream_t stream) {
  const float* x = (const float*)d_in[0];
  const float* W = (const float*)d_in[1];
  const float* b = (const float*)d_in[2];
  float* out = (float*)d_out;

  // ws layout (~1.66 MB)
  u16* Wp = (u16*)d_ws;                                   // 512 KB
  u16* Wlp = Wp + (size_t)E_NUM * D_DIM;                  // 512 KB
  float* top_p = (float*)(Wlp + (size_t)E_NUM * D_DIM);   // 64 KB
  int* top_i = (int*)(top_p + T_TOK);                     // 64 KB
  float* Spart = (float*)(top_i + T_TOK);                 // 256 KB
  float* Ppart = Spart + (size_t)NBLK * 64;               // 256 KB
  float* Stot = Ppart + (size_t)NBLK * 64;                // 256 B

  prep_kernel<<<128, 256, 0, stream>>>(W, Wp, Wlp);
  gemm_softmax<<<NBLK, 256, 0, stream>>>(x, Wp, Wlp, b, out, Spart, Ppart, top_p, top_i);
  aux_kernel<<<1, 256, 0, stream>>>(out, Spart, Ppart, Stot);
  finalize_kernel<<<T_TOK / 256, 256, 0, stream>>>(out, top_p, top_i, Stot);
}

// Round 3
// 408.474 us; speedup vs baseline: 1.0448x; 1.0335x over previous
//
#include <hip/hip_runtime.h>
#include <stdint.h>

// Problem constants (fixed by reference setup_inputs)
#define D_DIM 4096      // hidden dim (K)
#define E_NUM 64        // experts (N)
#define T_TOK 16384     // tokens (M) = 4*4096
#define CAPF 256.0f     // expert_capacity = int(16384/64*1.0)
#define ROWS 16         // tokens per block
#define NBLK (T_TOK / ROWS)   // 1024 blocks -> 4 blocks/CU -> 16 waves/CU

using bf16x8 = __attribute__((ext_vector_type(8))) short;
using f32x4  = __attribute__((ext_vector_type(4))) float;
typedef unsigned short u16;
typedef unsigned int u32;

// Truncation split: x == hi + lo exactly; lo then truncated to bf16 (err <= 2^-17 |x|).
__device__ __forceinline__ void cvt8(const float4 a, const float4 b, bf16x8& h, bf16x8& l) {
  float f[8] = {a.x, a.y, a.z, a.w, b.x, b.y, b.z, b.w};
#pragma unroll
  for (int i = 0; i < 8; ++i) {
    u32 u = __float_as_uint(f[i]);
    float lo = f[i] - __uint_as_float(u & 0xFFFF0000u);
    h[i] = (short)(u >> 16);
    l[i] = (short)(__float_as_uint(lo) >> 16);
  }
}

// Kernel 0: W (4096x64, [k][e]) -> Wp/Wlp packed in MFMA B-fragment order:
//   Wp[((kk*4 + ct)*64 + lane)*8 + i] = hi(W[kk*32 + (lane>>4)*8 + i][ct*16 + (lane&15)])
// so the GEMM's B-load is base + lane*16 (fully coalesced), no gathers.
__global__ __launch_bounds__(256) void prep_kernel(const float* __restrict__ W,
                                                   u16* __restrict__ Wp, u16* __restrict__ Wlp) {
  const int t = blockIdx.x * 256 + threadIdx.x;   // 32768 threads, one 16B chunk each
  const int lane = t & 63;
  const int ct = (t >> 6) & 3;
  const int kk = t >> 8;
  const int e = ct * 16 + (lane & 15);
  const int k0 = kk * 32 + (lane >> 4) * 8;
  u32 hp[4], lp[4];
#pragma unroll
  for (int j = 0; j < 4; ++j) {
    u32 hh[2], ll[2];
#pragma unroll
    for (int q = 0; q < 2; ++q) {
      float w = W[(size_t)(k0 + 2 * j + q) * E_NUM + e];
      u32 u = __float_as_uint(w);
      float lo = w - __uint_as_float(u & 0xFFFF0000u);
      hh[q] = u >> 16;
      ll[q] = __float_as_uint(lo) >> 16;
    }
    hp[j] = hh[0] | (hh[1] << 16);
    lp[j] = ll[0] | (ll[1] << 16);
  }
  *(uint4*)(Wp  + (size_t)t * 8) = make_uint4(hp[0], hp[1], hp[2], hp[3]);
  *(uint4*)(Wlp + (size_t)t * 8) = make_uint4(lp[0], lp[1], lp[2], lp[3]);
}

// Kernel 1: router GEMM + softmax + top-1.  16 tokens/block, 4 waves, wave kh
// owns the contiguous K-quarter [kh*1024, kh*1024+1024).  UNCHANGED from r2
// (single-variable round: the r2 aux_kernel reduced 512KB with ONE block —
// a likely 30-150us serial tail that masks whatever the r2 gemm changes did).
__global__ __launch_bounds__(256, 4) void gemm_softmax(
    const float* __restrict__ x, const u16* __restrict__ Wp, const u16* __restrict__ Wlp,
    const float* __restrict__ bias, float* __restrict__ out,
    float* __restrict__ Spart, float* __restrict__ Ppart,
    float* __restrict__ top_p, int* __restrict__ top_i) {
  __shared__ float smem[4 * 16 * 66];   // per-quarter partial logits slab (16.9 KB)
  __shared__ float S_loc[64];           // per-block top-prob sums (LDS atomics)

  const int tid = threadIdx.x;
  const int lane = tid & 63;
  const int kh = tid >> 6;       // K-quarter (wave id)
  const int m = lane & 15;       // token-in-tile (A row)
  const int g = lane >> 4;       // k-octet
  const int tok_base = blockIdx.x * ROWS;

  if (tid < 64) S_loc[tid] = 0.f;   // covered by the pre-epilogue barrier

  f32x4 acc[4];                  // [col-tile]
#pragma unroll
  for (int ct = 0; ct < 4; ++ct) acc[ct] = (f32x4){0.f, 0.f, 0.f, 0.f};

  // Per-lane A base: row tok_base+m, col kh*1024 + g*8.
  const float* pa = x + (size_t)(tok_base + m) * D_DIM + kh * 1024 + g * 8;

  float4 aA[2][2], aB[2][2];     // [j][half] — named buffers, no runtime idx

  auto loadA = [&](float4 (&dst)[2][2], int s) {
    const float* q = pa + s * 64;
    dst[0][0] = *(const float4*)(q);
    dst[0][1] = *(const float4*)(q + 4);
    dst[1][0] = *(const float4*)(q + 32);
    dst[1][1] = *(const float4*)(q + 36);
  };

  auto step = [&](const float4 (&af)[2][2], int s) {
#pragma unroll
    for (int j = 0; j < 2; ++j) {          // one k32-chunk per half-step
      const int kk = kh * 32 + s * 2 + j;
      bf16x8 bh[4], bl[4];
#pragma unroll
      for (int ct = 0; ct < 4; ++ct) {
        const size_t o = ((size_t)(kk * 4 + ct) * 64 + lane) * 8;
        bh[ct] = *(const bf16x8*)(Wp + o);
        bl[ct] = *(const bf16x8*)(Wlp + o);
      }
      bf16x8 ah, al;
      cvt8(af[j][0], af[j][1], ah, al);
#pragma unroll
      for (int ct = 0; ct < 4; ++ct) {
        acc[ct] = __builtin_amdgcn_mfma_f32_16x16x32_bf16(ah, bh[ct], acc[ct], 0, 0, 0);
        acc[ct] = __builtin_amdgcn_mfma_f32_16x16x32_bf16(al, bh[ct], acc[ct], 0, 0, 0);
        acc[ct] = __builtin_amdgcn_mfma_f32_16x16x32_bf16(ah, bl[ct], acc[ct], 0, 0, 0);
      }
    }
  };

  // Software pipeline, 2-deep A register double-buffer, no barriers.
  loadA(aA, 0);
#pragma unroll 1
  for (int s = 0; s < 16; s += 2) {        // 16 steps x 64 cols = 1024 cols
    loadA(aB, s + 1);
    step(aA, s);
    if (s + 2 < 16) loadA(aA, s + 2);
    step(aB, s + 1);
  }

  // ---- combine K-quarters via slab[4][16][66] ----
  // C/D layout: token-in-tile = g*4+r, expert-in-tile = ct*16+m (verified)
#pragma unroll
  for (int ct = 0; ct < 4; ++ct)
#pragma unroll
    for (int r = 0; r < 4; ++r)
      smem[kh * 1056 + (g * 4 + r) * 66 + ct * 16 + m] = acc[ct][r];
  __syncthreads();

  // softmax: 16 threads per token, 4 experts each
  const int j = tid >> 4;        // token 0..15
  const int q = tid & 15;
  float v[4];
#pragma unroll
  for (int i = 0; i < 4; ++i) {
    const int e = q * 4 + i;
    v[i] = bias[e] + smem[j * 66 + e] + smem[1056 + j * 66 + e]
                   + smem[2112 + j * 66 + e] + smem[3168 + j * 66 + e];
  }
  float best = v[0]; int bi = q * 4;
#pragma unroll
  for (int i = 1; i < 4; ++i)
    if (v[i] > best) { best = v[i]; bi = q * 4 + i; }
#pragma unroll
  for (int d = 1; d <= 8; d <<= 1) {   // reduce across the 16-lane token group
    float ob = __shfl_xor(best, d);
    int oi = __shfl_xor(bi, d);
    if (ob > best || (ob == best && oi < bi)) { best = ob; bi = oi; }
  }
  float ex[4], ssum = 0.f;
#pragma unroll
  for (int i = 0; i < 4; ++i) { ex[i] = __expf(v[i] - best); ssum += ex[i]; }
#pragma unroll
  for (int d = 1; d <= 8; d <<= 1) ssum += __shfl_xor(ssum, d);
  const float rs = 1.0f / ssum;

  const int gt = tok_base + j;
#pragma unroll
  for (int i = 0; i < 4; ++i) {
    float p = ex[i] * rs;
    out[(size_t)gt * 64 + q * 4 + i] = p;
    smem[j * 66 + q * 4 + i] = p;     // each thread rewrites exactly the slots it read
  }
  if (q == 0) {
    top_p[gt] = rs;                    // top prob = exp(best-best)/ssum
    top_i[gt] = bi;
    atomicAdd(&S_loc[bi], rs);         // LDS atomic — no global contention
  }
  __syncthreads();
  if (tid < 64) {                      // per-expert partials for this block
    float sa = 0.f;
#pragma unroll
    for (int jj = 0; jj < ROWS; ++jj) sa += smem[jj * 66 + tid];
    Ppart[(size_t)blockIdx.x * 64 + tid] = sa;
    Spart[(size_t)blockIdx.x * 64 + tid] = S_loc[tid];
  }
}

// Kernel 2a: parallel stage-1 reduction of per-block partials.
// 16 blocks x 256 thr; block b reduces gemm-blocks [b*64, b*64+64).
// Coalesced: a wave reads Spart[r][0..63] = 256B contiguous per load.
__global__ __launch_bounds__(256) void aux1_kernel(const float* __restrict__ Spart,
                                                   const float* __restrict__ Ppart,
                                                   float* __restrict__ Sred,
                                                   float* __restrict__ Pred) {
  __shared__ float sS[4][64], sP[4][64];
  const int l = threadIdx.x & 63;
  const int c = threadIdx.x >> 6;
  const int base = blockIdx.x * 64 + c * 16;
  float ss = 0.f, pp = 0.f;
#pragma unroll
  for (int r = 0; r < 16; ++r) {
    ss += Spart[(size_t)(base + r) * 64 + l];
    pp += Ppart[(size_t)(base + r) * 64 + l];
  }
  sS[c][l] = ss; sP[c][l] = pp;
  __syncthreads();
  if (threadIdx.x < 64) {
    Sred[(size_t)blockIdx.x * 64 + l] = sS[0][l] + sS[1][l] + sS[2][l] + sS[3][l];
    Pred[(size_t)blockIdx.x * 64 + l] = sP[0][l] + sP[1][l] + sP[2][l] + sP[3][l];
  }
}

// Kernel 2b: finish reduction (16x64x2 = 8KB), emit Stot + aux loss scalar.
__global__ __launch_bounds__(64) void aux2_kernel(float* __restrict__ out,
                                                  const float* __restrict__ Sred,
                                                  const float* __restrict__ Pred,
                                                  float* __restrict__ Stot) {
  const int l = threadIdx.x;
  float Sv = 0.f, Pv = 0.f;
#pragma unroll
  for (int b = 0; b < 16; ++b) {
    Sv += Sred[b * 64 + l];
    Pv += Pred[b * 64 + l];
  }
  Stot[l] = Sv;
  float v = Sv * Pv;
#pragma unroll
  for (int d = 1; d <= 32; d <<= 1) v += __shfl_xor(v, d);
  if (l == 0) out[(size_t)T_TOK * E_NUM] = 0.01f * 64.0f * v / ((float)T_TOK * (float)T_TOK);
}

// Kernel 3: capacity masking. Fast path: expert top-prob sum <= 256 -> all tokens kept
// (cumsum monotone, probs > 0). Exact O(T) scan only if an expert overflows.
__global__ __launch_bounds__(256) void finalize_kernel(float* __restrict__ out,
                                                       const float* __restrict__ top_p,
                                                       const int* __restrict__ top_i,
                                                       const float* __restrict__ Stot) {
  int t = blockIdx.x * 256 + threadIdx.x;
  int e = top_i[t];
  float se = Stot[e];
  if (se > CAPF) {
    float p = top_p[t];
    float G = 0.f;
    for (int u = 0; u < T_TOK; ++u) {
      if (top_i[u] == e) {
        float q = top_p[u];
        if (q > p || (q == p && u <= t)) G += q;
      }
    }
    if (G > CAPF) {
      float4 z = {0.f, 0.f, 0.f, 0.f};
      float4* row = (float4*)(out + (size_t)t * 64);
#pragma unroll
      for (int i = 0; i < 16; ++i) row[i] = z;
    }
  }
}

extern "C" void kernel_launch(void* const* d_in, const int* in_sizes, int n_in,
                              void* d_out, int out_size, void* d_ws, size_t ws_size,
                              hipStream_t stream) {
  const float* x = (const float*)d_in[0];
  const float* W = (const float*)d_in[1];
  const float* b = (const float*)d_in[2];
  float* out = (float*)d_out;

  // ws layout (~1.68 MB)
  u16* Wp = (u16*)d_ws;                                   // 512 KB
  u16* Wlp = Wp + (size_t)E_NUM * D_DIM;                  // 512 KB
  float* top_p = (float*)(Wlp + (size_t)E_NUM * D_DIM);   // 64 KB
  int* top_i = (int*)(top_p + T_TOK);                     // 64 KB
  float* Spart = (float*)(top_i + T_TOK);                 // 256 KB
  float* Ppart = Spart + (size_t)NBLK * 64;               // 256 KB
  float* Sred = Ppart + (size_t)NBLK * 64;                // 4 KB
  float* Pred = Sred + 16 * 64;                           // 4 KB
  float* Stot = Pred + 16 * 64;                           // 256 B

  prep_kernel<<<128, 256, 0, stream>>>(W, Wp, Wlp);
  gemm_softmax<<<NBLK, 256, 0, stream>>>(x, Wp, Wlp, b, out, Spart, Ppart, top_p, top_i);
  aux1_kernel<<<16, 256, 0, stream>>>(Spart, Ppart, Sred, Pred);
  aux2_kernel<<<1, 64, 0, stream>>>(out, Sred, Pred, Stot);
  finalize_kernel<<<T_TOK / 256, 256, 0, stream>>>(out, top_p, top_i, Stot);
}